// Round 5
// baseline (1610.067 us; speedup 1.0000x reference)
//
#include <hip/hip_runtime.h>
#include <math.h>

#define T_TOK 32768
#define DIM   2048
#define E_N   64
#define KP    2048   // padded reduction length (col 0 of wpad is zero)
#define BR    64     // rows per block (4 waves x 16 rows)

// ws layout (floats): [0, 131072) wpad[64][2048]; [131072, +32768*64) logits
#define WS_WPAD_FLOATS (E_N * KP)

typedef float v4f __attribute__((ext_vector_type(4)));

#define FMA4(A, X, W_) do {                                            \
    (A) = fmaf((X).x, (W_).x, (A)); (A) = fmaf((X).y, (W_).y, (A));    \
    (A) = fmaf((X).z, (W_).z, (A)); (A) = fmaf((X).w, (W_).w, (A)); } while (0)

// ---------------- kernel 0: shift/pad weight ----------------
__global__ __launch_bounds__(256) void k_padw(const float* __restrict__ w,
                                              float* __restrict__ wpad) {
  int idx = blockIdx.x * 256 + threadIdx.x;   // 0 .. 64*2048-1
  int e = idx >> 11;
  int c = idx & 2047;
  wpad[idx] = (c == 0) ? 0.f : w[e * 2047 + (c - 1)];
}

// ---------------- kernel 1: logits = x[:,1:] @ W^T ----------------
// 4-slot software-pipelined register double... quad-buffer. No LDS, no
// barriers, no nontemporal (x should L3-cache across replays; W stays L2-hot).
// lane = (eg<<2)|rg : rows row0+{0..3} (row0 = blk*64 + w*16 + rg*4),
// experts eg*4+{0..3} (4 consecutive lanes share eg -> W broadcast load;
// 16 lanes share rg -> x broadcast load).
__global__ __launch_bounds__(256, 2) void k_logits(const float* __restrict__ x,
                                                   const float* __restrict__ wpad,
                                                   float* __restrict__ logits) {
  const int tid  = threadIdx.x;
  const int w    = tid >> 6;
  const int lane = tid & 63;
  const int rg   = lane & 3;
  const int eg   = lane >> 2;      // 0..15
  const int row0 = blockIdx.x * BR + w * 16 + rg * 4;

  const float* xp0 = x + (size_t)row0 * DIM;
  const float* xp1 = xp0 + DIM;
  const float* xp2 = xp0 + 2 * DIM;
  const float* xp3 = xp0 + 3 * DIM;
  const float* wp0 = wpad + (size_t)(eg * 4 + 0) * KP;
  const float* wp1 = wp0 + KP;
  const float* wp2 = wp0 + 2 * KP;
  const float* wp3 = wp0 + 3 * KP;

  v4f xs[4][4];   // [slot][row]
  v4f ws[4][4];   // [slot][expert]
  float acc[4][4];
#pragma unroll
  for (int r = 0; r < 4; ++r)
#pragma unroll
    for (int e = 0; e < 4; ++e) acc[r][e] = 0.f;

  // prologue: slot j holds c4-index j (float offset j*4)
#pragma unroll
  for (int j = 0; j < 4; ++j) {
    xs[j][0] = *(const v4f*)(xp0 + j * 4);
    xs[j][1] = *(const v4f*)(xp1 + j * 4);
    xs[j][2] = *(const v4f*)(xp2 + j * 4);
    xs[j][3] = *(const v4f*)(xp3 + j * 4);
    ws[j][0] = *(const v4f*)(wp0 + j * 4);
    ws[j][1] = *(const v4f*)(wp1 + j * 4);
    ws[j][2] = *(const v4f*)(wp2 + j * 4);
    ws[j][3] = *(const v4f*)(wp3 + j * 4);
  }

  // 128 groups of 4 c4-bodies; groups 0..126 prefetch group g+1 (ascending k
  // order per accumulator -> bitwise-identical logits to the passing R4 run)
  for (int g = 0; g < 127; ++g) {
#pragma unroll
    for (int j = 0; j < 4; ++j) {
#pragma unroll
      for (int e = 0; e < 4; ++e) {
        FMA4(acc[0][e], xs[j][0], ws[j][e]);
        FMA4(acc[1][e], xs[j][1], ws[j][e]);
        FMA4(acc[2][e], xs[j][2], ws[j][e]);
        FMA4(acc[3][e], xs[j][3], ws[j][e]);
      }
      const int o = 16 + j * 4;   // same slot, next group (imm offsets 64..112B)
      xs[j][0] = *(const v4f*)(xp0 + o);
      xs[j][1] = *(const v4f*)(xp1 + o);
      xs[j][2] = *(const v4f*)(xp2 + o);
      xs[j][3] = *(const v4f*)(xp3 + o);
      ws[j][0] = *(const v4f*)(wp0 + o);
      ws[j][1] = *(const v4f*)(wp1 + o);
      ws[j][2] = *(const v4f*)(wp2 + o);
      ws[j][3] = *(const v4f*)(wp3 + o);
    }
    xp0 += 16; xp1 += 16; xp2 += 16; xp3 += 16;
    wp0 += 16; wp1 += 16; wp2 += 16; wp3 += 16;
  }
  // final group: compute only, no prefetch (no OOB)
#pragma unroll
  for (int j = 0; j < 4; ++j) {
#pragma unroll
    for (int e = 0; e < 4; ++e) {
      FMA4(acc[0][e], xs[j][0], ws[j][e]);
      FMA4(acc[1][e], xs[j][1], ws[j][e]);
      FMA4(acc[2][e], xs[j][2], ws[j][e]);
      FMA4(acc[3][e], xs[j][3], ws[j][e]);
    }
  }

#pragma unroll
  for (int r = 0; r < 4; ++r) {
    v4f ov;
    ov.x = acc[r][0]; ov.y = acc[r][1]; ov.z = acc[r][2]; ov.w = acc[r][3];
    *(v4f*)(logits + (size_t)(row0 + r) * E_N + eg * 4) = ov;
  }
}

// ---------------- kernel 2: per-row group-limited top-k routing ----------------
__global__ __launch_bounds__(256) void k_route(const float* __restrict__ logits,
                                               const float* __restrict__ bias,
                                               float* __restrict__ out_w,
                                               float* __restrict__ out_i) {
  __shared__ float bl[E_N];
  if (threadIdx.x < E_N) bl[threadIdx.x] = bias[threadIdx.x];
  __syncthreads();

  const int row = blockIdx.x * 256 + threadIdx.x;      // grid sized exactly
  const float* lp = logits + (size_t)row * E_N;

  float sb[E_N];                                       // sigmoid(logit) + bias
#pragma unroll
  for (int e4 = 0; e4 < 16; ++e4) {
    float4 lv = *(const float4*)(lp + e4 * 4);
    sb[e4 * 4 + 0] = 1.f / (1.f + expf(-lv.x)) + bl[e4 * 4 + 0];
    sb[e4 * 4 + 1] = 1.f / (1.f + expf(-lv.y)) + bl[e4 * 4 + 1];
    sb[e4 * 4 + 2] = 1.f / (1.f + expf(-lv.z)) + bl[e4 * 4 + 2];
    sb[e4 * 4 + 3] = 1.f / (1.f + expf(-lv.w)) + bl[e4 * 4 + 3];
  }

  // group scores: sum of top-2 per group of 8
  float gs[8];
#pragma unroll
  for (int g = 0; g < 8; ++g) {
    float m1 = -__builtin_inff(), m2 = -__builtin_inff();
#pragma unroll
    for (int j = 0; j < 8; ++j) {
      float v = sb[g * 8 + j];
      if (v > m1) { m2 = m1; m1 = v; }
      else if (v > m2) { m2 = v; }
    }
    gs[g] = m1 + m2;
  }

  // top-4 groups (strict > : lower index wins ties, matches lax.top_k)
  unsigned gmask = 0;
#pragma unroll
  for (int tsel = 0; tsel < 4; ++tsel) {
    float best = -__builtin_inff(); int bi = 0;
#pragma unroll
    for (int g = 0; g < 8; ++g) {
      bool avail = ((gmask >> g) & 1u) == 0u;
      if (avail && gs[g] > best) { best = gs[g]; bi = g; }
    }
    gmask |= (1u << bi);
  }

  // taken-mask: pre-ban experts in dropped groups
  unsigned long long tm = 0ull;
#pragma unroll
  for (int g = 0; g < 8; ++g)
    if (((gmask >> g) & 1u) == 0u) tm |= (0xFFull << (8 * g));

  // top-8 experts over allowed groups
  float wv[8]; int io[8]; float wsum = 0.f;
#pragma unroll
  for (int tsel = 0; tsel < 8; ++tsel) {
    float best = -__builtin_inff(); int bi = 0;
#pragma unroll
    for (int e = 0; e < E_N; ++e) {
      bool avail = ((tm >> e) & 1ull) == 0ull;
      if (avail && sb[e] > best) { best = sb[e]; bi = e; }
    }
    tm |= (1ull << bi);
    float sv = best - bl[bi];        // original sigmoid score (bias removed)
    wv[tsel] = sv; io[tsel] = bi; wsum += sv;
  }

  const float scale = 2.5f / wsum;
  float4 w0 = make_float4(wv[0] * scale, wv[1] * scale, wv[2] * scale, wv[3] * scale);
  float4 w1 = make_float4(wv[4] * scale, wv[5] * scale, wv[6] * scale, wv[7] * scale);
  float4 i0 = make_float4((float)io[0], (float)io[1], (float)io[2], (float)io[3]);
  float4 i1 = make_float4((float)io[4], (float)io[5], (float)io[6], (float)io[7]);
  *(float4*)(out_w + (size_t)row * 8)     = w0;
  *(float4*)(out_w + (size_t)row * 8 + 4) = w1;
  *(float4*)(out_i + (size_t)row * 8)     = i0;
  *(float4*)(out_i + (size_t)row * 8 + 4) = i1;
}

extern "C" void kernel_launch(void* const* d_in, const int* in_sizes, int n_in,
                              void* d_out, int out_size, void* d_ws, size_t ws_size,
                              hipStream_t stream) {
  const float* x    = (const float*)d_in[0];
  const float* wgt  = (const float*)d_in[1];
  const float* bias = (const float*)d_in[2];
  float* out    = (float*)d_out;
  float* wpad   = (float*)d_ws;
  float* logits = (float*)d_ws + WS_WPAD_FLOATS;

  k_padw  <<<(E_N * KP) / 256, 256, 0, stream>>>(wgt, wpad);
  k_logits<<<T_TOK / BR,      256, 0, stream>>>(x, wpad, logits);
  k_route <<<T_TOK / 256,     256, 0, stream>>>(logits, bias,
                                                out, out + (size_t)T_TOK * 8);
}

// Round 6
// 192.243 us; speedup vs baseline: 8.3752x; 8.3752x over previous
//
#include <hip/hip_runtime.h>
#include <math.h>

#define T_TOK 32768
#define DIM   2048
#define E_N   64
#define KP    2048   // padded reduction length (row 0 of Wt is zero)

// ws layout (floats): [0, 131072) Wt[2048][64]; [131072, +32768*64) logitsT[64][T]
#define WS_WT_FLOATS (KP * E_N)

typedef float v4f __attribute__((ext_vector_type(4)));

// ---------------- kernel 0: shift/pad + transpose weight -> Wt[k][e] ----------------
__global__ __launch_bounds__(256) void k_padw(const float* __restrict__ w,
                                              float* __restrict__ wt) {
  int idx = blockIdx.x * 256 + threadIdx.x;   // 0 .. 2048*64-1
  int k = idx >> 6;
  int e = idx & 63;
  wt[idx] = (k == 0) ? 0.f : w[e * 2047 + (k - 1)];
}

// ---------------- kernel 1: logitsT = (x[:,1:] @ W^T)^T ----------------
// Row-per-lane, weights-in-SGPR structure. Block = 64 rows (row = blk*64+lane,
// identical for all 4 waves); wave w owns k in [w*512, (w+1)*512). Each lane:
// 64 fp32 accumulators (one per expert); per 16-k group it loads 4 dwordx4
// from ITS OWN row (one 64B line, fetched once) and does 1024 FMAs with
// wave-uniform W values (s_load from transposed Wt). No barriers in the main
// loop; one __syncthreads before the LDS cross-wave k-reduce.
__global__ __launch_bounds__(256, 4) void k_logits(const float* __restrict__ x,
                                                   const float* __restrict__ wt,
                                                   float* __restrict__ logitsT) {
  __shared__ float buf[4][E_N][64];   // [wave][expert][row-lane] = 64 KB
  const int tid  = threadIdx.x;
  const int lane = tid & 63;
  const int wv   = __builtin_amdgcn_readfirstlane(tid >> 6);  // SGPR wave id
  const int kbase = wv * 512;
  const int row  = blockIdx.x * 64 + lane;

  const float* xp = x + (size_t)row * DIM + kbase;   // per-lane (divergent)
  const float* wkbase = wt + (size_t)kbase * E_N;    // wave-uniform (SGPR)

  float acc[E_N];
#pragma unroll
  for (int e = 0; e < E_N; ++e) acc[e] = 0.f;

  for (int g = 0; g < 32; ++g) {       // 32 groups x 16 k = 512 k per wave
    v4f xv[4];
#pragma unroll
    for (int q = 0; q < 4; ++q)
      xv[q] = *(const v4f*)(xp + q * 4);   // same 64B line, 4 loads
    const float* wk = wkbase + g * 16 * E_N;   // uniform
#pragma unroll
    for (int q = 0; q < 4; ++q) {
#pragma unroll
      for (int kk = 0; kk < 4; ++kk) {
        const float xk = xv[q][kk];
        const float* wrow = wk + (q * 4 + kk) * E_N;   // uniform -> s_load
#pragma unroll
        for (int e = 0; e < E_N; ++e)
          acc[e] = fmaf(xk, wrow[e], acc[e]);
      }
    }
    xp += 16;
  }

  // cross-wave k-reduce via LDS (conflict-free: lane-contiguous rows)
#pragma unroll
  for (int e = 0; e < E_N; ++e)
    buf[wv][e][lane] = acc[e];
  __syncthreads();

  // thread (r = tid&63) sums 16 experts, stores lane-contiguous to logitsT
  const int r   = tid & 63;
  const int ew0 = (tid >> 6) * 16;
#pragma unroll
  for (int i = 0; i < 16; ++i) {
    const int e = ew0 + i;
    const float v = ((buf[0][e][r] + buf[1][e][r]) + buf[2][e][r]) + buf[3][e][r];
    logitsT[(size_t)e * T_TOK + blockIdx.x * 64 + r] = v;
  }
}

// ---------------- kernel 2: per-row group-limited top-k routing ----------------
__global__ __launch_bounds__(256) void k_route(const float* __restrict__ logitsT,
                                               const float* __restrict__ bias,
                                               float* __restrict__ out_w,
                                               float* __restrict__ out_i) {
  __shared__ float bl[E_N];
  if (threadIdx.x < E_N) bl[threadIdx.x] = bias[threadIdx.x];
  __syncthreads();

  const int row = blockIdx.x * 256 + threadIdx.x;      // grid sized exactly
  const float* lp = logitsT + row;                     // column access: lane-coalesced

  float sb[E_N];                                       // sigmoid(logit) + bias
#pragma unroll
  for (int e = 0; e < E_N; ++e)
    sb[e] = 1.f / (1.f + expf(-lp[(size_t)e * T_TOK])) + bl[e];

  // group scores: sum of top-2 per group of 8
  float gs[8];
#pragma unroll
  for (int g = 0; g < 8; ++g) {
    float m1 = -__builtin_inff(), m2 = -__builtin_inff();
#pragma unroll
    for (int j = 0; j < 8; ++j) {
      float v = sb[g * 8 + j];
      if (v > m1) { m2 = m1; m1 = v; }
      else if (v > m2) { m2 = v; }
    }
    gs[g] = m1 + m2;
  }

  // top-4 groups (strict > : lower index wins ties, matches lax.top_k)
  unsigned gmask = 0;
#pragma unroll
  for (int tsel = 0; tsel < 4; ++tsel) {
    float best = -__builtin_inff(); int bi = 0;
#pragma unroll
    for (int g = 0; g < 8; ++g) {
      bool avail = ((gmask >> g) & 1u) == 0u;
      if (avail && gs[g] > best) { best = gs[g]; bi = g; }
    }
    gmask |= (1u << bi);
  }

  // taken-mask: pre-ban experts in dropped groups
  unsigned long long tm = 0ull;
#pragma unroll
  for (int g = 0; g < 8; ++g)
    if (((gmask >> g) & 1u) == 0u) tm |= (0xFFull << (8 * g));

  // top-8 experts over allowed groups
  float wv[8]; int io[8]; float wsum = 0.f;
#pragma unroll
  for (int tsel = 0; tsel < 8; ++tsel) {
    float best = -__builtin_inff(); int bi = 0;
#pragma unroll
    for (int e = 0; e < E_N; ++e) {
      bool avail = ((tm >> e) & 1ull) == 0ull;
      if (avail && sb[e] > best) { best = sb[e]; bi = e; }
    }
    tm |= (1ull << bi);
    float sv = best - bl[bi];        // original sigmoid score (bias removed)
    wv[tsel] = sv; io[tsel] = bi; wsum += sv;
  }

  const float scale = 2.5f / wsum;
  float4 w0 = make_float4(wv[0] * scale, wv[1] * scale, wv[2] * scale, wv[3] * scale);
  float4 w1 = make_float4(wv[4] * scale, wv[5] * scale, wv[6] * scale, wv[7] * scale);
  float4 i0 = make_float4((float)io[0], (float)io[1], (float)io[2], (float)io[3]);
  float4 i1 = make_float4((float)io[4], (float)io[5], (float)io[6], (float)io[7]);
  *(float4*)(out_w + (size_t)row * 8)     = w0;
  *(float4*)(out_w + (size_t)row * 8 + 4) = w1;
  *(float4*)(out_i + (size_t)row * 8)     = i0;
  *(float4*)(out_i + (size_t)row * 8 + 4) = i1;
}

extern "C" void kernel_launch(void* const* d_in, const int* in_sizes, int n_in,
                              void* d_out, int out_size, void* d_ws, size_t ws_size,
                              hipStream_t stream) {
  const float* x    = (const float*)d_in[0];
  const float* wgt  = (const float*)d_in[1];
  const float* bias = (const float*)d_in[2];
  float* out     = (float*)d_out;
  float* wtbuf   = (float*)d_ws;
  float* logitsT = (float*)d_ws + WS_WT_FLOATS;

  k_padw  <<<(KP * E_N) / 256, 256, 0, stream>>>(wgt, wtbuf);
  k_logits<<<T_TOK / 64,       256, 0, stream>>>(x, wtbuf, logitsT);
  k_route <<<T_TOK / 256,      256, 0, stream>>>(logitsT, bias,
                                                 out, out + (size_t)T_TOK * 8);
}

// Round 7
// 141.401 us; speedup vs baseline: 11.3865x; 1.3596x over previous
//
#include <hip/hip_runtime.h>
#include <math.h>

#define T_TOK 32768
#define DIM   2048
#define E_N   64
#define KP    2048   // padded reduction length (row 0 of Wt is zero)

// ws layout (floats): [0, 131072) Wt[2048][64]; [131072, +32768*64) logitsT[64][T]
#define WS_WT_FLOATS (KP * E_N)

typedef float v4f __attribute__((ext_vector_type(4)));

// ---------------- kernel 0: shift/pad + transpose weight -> Wt[k][e] ----------------
__global__ __launch_bounds__(256) void k_padw(const float* __restrict__ w,
                                              float* __restrict__ wt) {
  int idx = blockIdx.x * 256 + threadIdx.x;   // 0 .. 2048*64-1
  int k = idx >> 6;
  int e = idx & 63;
  wt[idx] = (k == 0) ? 0.f : w[e * 2047 + (k - 1)];
}

// ---------------- kernel 1: logitsT = (x[:,1:] @ W^T)^T ----------------
// Row-per-lane, weights-in-SGPR. Block = 64 rows, 8 waves; wave w owns
// k in [w*256, (w+1)*256). 2 blocks/CU -> 16 waves/CU = 4/SIMD so the
// s_load(W)->fmac serialization of one wave hides under the other three.
// Two-stage LDS reduce keeps LDS at 64 KB (2 blocks/CU).
__global__ __launch_bounds__(512, 4) void k_logits(const float* __restrict__ x,
                                                   const float* __restrict__ wt,
                                                   float* __restrict__ logitsT) {
  __shared__ float buf[4][E_N][64];   // 64 KB
  const int tid  = threadIdx.x;
  const int lane = tid & 63;
  const int wv   = __builtin_amdgcn_readfirstlane(tid >> 6);  // 0..7 (SGPR)
  const int kbase = wv * 256;
  const int row  = blockIdx.x * 64 + lane;

  const float* xp = x + (size_t)row * DIM + kbase;   // per-lane (divergent)
  const float* wkbase = wt + (size_t)kbase * E_N;    // wave-uniform (SGPR)

  float acc[E_N];
#pragma unroll
  for (int e = 0; e < E_N; ++e) acc[e] = 0.f;

  for (int g = 0; g < 16; ++g) {       // 16 groups x 16 k = 256 k per wave
    v4f xv[4];
#pragma unroll
    for (int q = 0; q < 4; ++q)
      xv[q] = *(const v4f*)(xp + q * 4);   // same 64B line, 4 loads
    const float* wk = wkbase + g * 16 * E_N;   // uniform
#pragma unroll
    for (int q = 0; q < 4; ++q) {
#pragma unroll
      for (int kk = 0; kk < 4; ++kk) {
        const float xk = xv[q][kk];
        const float* wrow = wk + (q * 4 + kk) * E_N;   // uniform -> s_load
#pragma unroll
        for (int e = 0; e < E_N; ++e)
          acc[e] = fmaf(xk, wrow[e], acc[e]);
      }
    }
    xp += 16;
  }

  // two-stage cross-wave k-reduce (lane-contiguous rows: conflict-free)
  if (wv < 4) {
#pragma unroll
    for (int e = 0; e < E_N; ++e)
      buf[wv][e][lane] = acc[e];
  }
  __syncthreads();
  if (wv >= 4) {
#pragma unroll
    for (int e = 0; e < E_N; ++e)
      buf[wv - 4][e][lane] += acc[e];
  }
  __syncthreads();

  // epilogue: 512 threads, 8 experts each, lane-contiguous stores
  const int r  = tid & 63;
  const int e0 = (tid >> 6) * 8;
#pragma unroll
  for (int i = 0; i < 8; ++i) {
    const int e = e0 + i;
    const float v = ((buf[0][e][r] + buf[1][e][r]) + buf[2][e][r]) + buf[3][e][r];
    logitsT[(size_t)e * T_TOK + blockIdx.x * 64 + r] = v;
  }
}

// ---------------- kernel 2: per-row group-limited top-k routing ----------------
__global__ __launch_bounds__(256) void k_route(const float* __restrict__ logitsT,
                                               const float* __restrict__ bias,
                                               float* __restrict__ out_w,
                                               float* __restrict__ out_i) {
  __shared__ float bl[E_N];
  if (threadIdx.x < E_N) bl[threadIdx.x] = bias[threadIdx.x];
  __syncthreads();

  const int row = blockIdx.x * 256 + threadIdx.x;      // grid sized exactly
  const float* lp = logitsT + row;                     // column access: lane-coalesced

  float sb[E_N];                                       // sigmoid(logit) + bias
#pragma unroll
  for (int e = 0; e < E_N; ++e)
    sb[e] = 1.f / (1.f + expf(-lp[(size_t)e * T_TOK])) + bl[e];

  // group scores: sum of top-2 per group of 8
  float gs[8];
#pragma unroll
  for (int g = 0; g < 8; ++g) {
    float m1 = -__builtin_inff(), m2 = -__builtin_inff();
#pragma unroll
    for (int j = 0; j < 8; ++j) {
      float v = sb[g * 8 + j];
      if (v > m1) { m2 = m1; m1 = v; }
      else if (v > m2) { m2 = v; }
    }
    gs[g] = m1 + m2;
  }

  // top-4 groups (strict > : lower index wins ties, matches lax.top_k)
  unsigned gmask = 0;
#pragma unroll
  for (int tsel = 0; tsel < 4; ++tsel) {
    float best = -__builtin_inff(); int bi = 0;
#pragma unroll
    for (int g = 0; g < 8; ++g) {
      bool avail = ((gmask >> g) & 1u) == 0u;
      if (avail && gs[g] > best) { best = gs[g]; bi = g; }
    }
    gmask |= (1u << bi);
  }

  // taken-mask: pre-ban experts in dropped groups
  unsigned long long tm = 0ull;
#pragma unroll
  for (int g = 0; g < 8; ++g)
    if (((gmask >> g) & 1u) == 0u) tm |= (0xFFull << (8 * g));

  // top-8 experts over allowed groups
  float wv[8]; int io[8]; float wsum = 0.f;
#pragma unroll
  for (int tsel = 0; tsel < 8; ++tsel) {
    float best = -__builtin_inff(); int bi = 0;
#pragma unroll
    for (int e = 0; e < E_N; ++e) {
      bool avail = ((tm >> e) & 1ull) == 0ull;
      if (avail && sb[e] > best) { best = sb[e]; bi = e; }
    }
    tm |= (1ull << bi);
    float sv = best - bl[bi];        // original sigmoid score (bias removed)
    wv[tsel] = sv; io[tsel] = bi; wsum += sv;
  }

  const float scale = 2.5f / wsum;
  float4 w0 = make_float4(wv[0] * scale, wv[1] * scale, wv[2] * scale, wv[3] * scale);
  float4 w1 = make_float4(wv[4] * scale, wv[5] * scale, wv[6] * scale, wv[7] * scale);
  float4 i0 = make_float4((float)io[0], (float)io[1], (float)io[2], (float)io[3]);
  float4 i1 = make_float4((float)io[4], (float)io[5], (float)io[6], (float)io[7]);
  *(float4*)(out_w + (size_t)row * 8)     = w0;
  *(float4*)(out_w + (size_t)row * 8 + 4) = w1;
  *(float4*)(out_i + (size_t)row * 8)     = i0;
  *(float4*)(out_i + (size_t)row * 8 + 4) = i1;
}

extern "C" void kernel_launch(void* const* d_in, const int* in_sizes, int n_in,
                              void* d_out, int out_size, void* d_ws, size_t ws_size,
                              hipStream_t stream) {
  const float* x    = (const float*)d_in[0];
  const float* wgt  = (const float*)d_in[1];
  const float* bias = (const float*)d_in[2];
  float* out     = (float*)d_out;
  float* wtbuf   = (float*)d_ws;
  float* logitsT = (float*)d_ws + WS_WT_FLOATS;

  k_padw  <<<(KP * E_N) / 256, 256, 0, stream>>>(wgt, wtbuf);
  k_logits<<<T_TOK / 64,       512, 0, stream>>>(x, wtbuf, logitsT);
  k_route <<<T_TOK / 256,      256, 0, stream>>>(logitsT, bias,
                                                 out, out + (size_t)T_TOK * 8);
}